// Round 1
// baseline (206.874 us; speedup 1.0000x reference)
//
#include <hip/hip_runtime.h>
#include <stdint.h>

#define N_ROWS   16384
#define IN_DIM   512
#define CB_DIM   16
#define CB_VOCAB 8192

#define CODES_PER_CHUNK 128
#define NCHUNKS (CB_VOCAB / CODES_PER_CHUNK)        // 64
#define ROWS_PER_LANE 8
#define WAVES_PER_BLOCK 4
#define ROWS_PER_WAVE (64 * ROWS_PER_LANE)          // 512
#define ROWS_PER_BLOCK (ROWS_PER_WAVE * WAVES_PER_BLOCK) // 2048
#define ROW_BLOCKS (N_ROWS / ROWS_PER_BLOCK)        // 8

// workspace layout (bytes)
#define WS_OFF_PT   0                               // 16*512*4 = 32768
#define WS_OFF_XP   65536                           // 16384*16*4 = 1 MB
#define WS_OFF_PART 1114112                         // 64*16384*8 = 8 MB

// monotone float -> uint32 key (order-preserving for all finite floats)
__device__ __forceinline__ unsigned fkey(float f) {
    unsigned u = __float_as_uint(f);
    return (u & 0x80000000u) ? ~u : (u | 0x80000000u);
}

// ---------------- kernel 0: transpose P [512,16] -> Pt [16,512] -------------
__global__ void k_transpose_P(const float* __restrict__ P, float* __restrict__ Pt) {
    int t = blockIdx.x * 256 + threadIdx.x;          // [0, 8192)
    int i = t >> 4;
    int c = t & 15;
    Pt[c * IN_DIM + i] = P[t];
}

// ---------------- kernel 1: xp = x @ P  (thread per (row, c)) ---------------
__global__ __launch_bounds__(256, 4)
void k_proj(const float* __restrict__ x, const float* __restrict__ Pt,
            float* __restrict__ xp) {
    int t = blockIdx.x * 256 + threadIdx.x;          // [0, 262144)
    int row = t >> 4;
    int c = t & 15;
    const float4* xr = (const float4*)(x + (size_t)row * IN_DIM);
    const float4* pr = (const float4*)(Pt + (size_t)c * IN_DIM);
    float acc = 0.0f;
#pragma unroll 4
    for (int k = 0; k < IN_DIM / 4; ++k) {
        float4 a = xr[k];
        float4 b = pr[k];
        acc += a.x * b.x + a.y * b.y + a.z * b.z + a.w * b.w;
    }
    xp[t] = acc;
}

// ---------------- kernel 2: fused sim + per-chunk argmax --------------------
// grid: ROW_BLOCKS * NCHUNKS blocks of 256 threads (4 waves)
// each lane owns 8 rows (xp in regs); codes of the chunk broadcast from LDS.
__global__ __launch_bounds__(256, 2)
void k_scan(const float* __restrict__ xp, const float* __restrict__ CB,
            unsigned long long* __restrict__ part) {
    __shared__ float4 cbs[CODES_PER_CHUNK * 4];      // 128 codes * 16 f32 = 8 KB

    int chunk  = blockIdx.x & (NCHUNKS - 1);
    int rowblk = blockIdx.x >> 6;                    // / NCHUNKS

    // stage codebook chunk -> LDS (coalesced float4)
    {
        const float4* src = (const float4*)(CB + (size_t)chunk * CODES_PER_CHUNK * CB_DIM);
        for (int i = threadIdx.x; i < CODES_PER_CHUNK * 4; i += 256)
            cbs[i] = src[i];
    }
    __syncthreads();

    int wave = threadIdx.x >> 6;
    int lane = threadIdx.x & 63;
    int rowbase = rowblk * ROWS_PER_BLOCK + wave * ROWS_PER_WAVE + lane;

    // load 8 rows of xp into registers (coalesced: lanes stride 64 B)
    float4 A[ROWS_PER_LANE][4];
#pragma unroll
    for (int r = 0; r < ROWS_PER_LANE; ++r) {
        const float4* p = (const float4*)(xp + (size_t)(rowbase + 64 * r) * CB_DIM);
        A[r][0] = p[0]; A[r][1] = p[1]; A[r][2] = p[2]; A[r][3] = p[3];
    }

    float bestv[ROWS_PER_LANE];
    int   besti[ROWS_PER_LANE];
#pragma unroll
    for (int r = 0; r < ROWS_PER_LANE; ++r) { bestv[r] = -INFINITY; besti[r] = 0; }

    int jbase = chunk * CODES_PER_CHUNK;
    for (int j = 0; j < CODES_PER_CHUNK; ++j) {
        float4 c0 = cbs[j * 4 + 0];
        float4 c1 = cbs[j * 4 + 1];
        float4 c2 = cbs[j * 4 + 2];
        float4 c3 = cbs[j * 4 + 3];
#pragma unroll
        for (int r = 0; r < ROWS_PER_LANE; ++r) {
            float s = A[r][0].x * c0.x + A[r][0].y * c0.y + A[r][0].z * c0.z + A[r][0].w * c0.w
                    + A[r][1].x * c1.x + A[r][1].y * c1.y + A[r][1].z * c1.z + A[r][1].w * c1.w
                    + A[r][2].x * c2.x + A[r][2].y * c2.y + A[r][2].z * c2.z + A[r][2].w * c2.w
                    + A[r][3].x * c3.x + A[r][3].y * c3.y + A[r][3].z * c3.z + A[r][3].w * c3.w;
            if (s > bestv[r]) { bestv[r] = s; besti[r] = jbase + j; }  // strict > : first occurrence wins
        }
    }

    // pack (key << 32) | ~idx : max-reduce picks larger value, then smaller idx
#pragma unroll
    for (int r = 0; r < ROWS_PER_LANE; ++r) {
        unsigned long long packed =
            ((unsigned long long)fkey(bestv[r]) << 32) |
            (unsigned long long)(0xFFFFFFFFu - (unsigned)besti[r]);
        part[(size_t)chunk * N_ROWS + rowbase + 64 * r] = packed;
    }
}

// ---------------- kernel 3: reduce partials -> int32 indices ----------------
__global__ void k_reduce(const unsigned long long* __restrict__ part,
                         int* __restrict__ out) {
    int row = blockIdx.x * 256 + threadIdx.x;        // [0, 16384)
    unsigned long long best = 0ull;
#pragma unroll 8
    for (int c = 0; c < NCHUNKS; ++c) {
        unsigned long long v = part[(size_t)c * N_ROWS + row];
        best = (v > best) ? v : best;
    }
    out[row] = (int)(0xFFFFFFFFu - (unsigned)(best & 0xFFFFFFFFull));
}

extern "C" void kernel_launch(void* const* d_in, const int* in_sizes, int n_in,
                              void* d_out, int out_size, void* d_ws, size_t ws_size,
                              hipStream_t stream) {
    const float* x  = (const float*)d_in[0];   // [16384, 512]
    const float* P  = (const float*)d_in[1];   // [512, 16]
    const float* CB = (const float*)d_in[2];   // [8192, 16]
    int* out = (int*)d_out;                    // [16384] int32

    char* ws = (char*)d_ws;
    float* Pt = (float*)(ws + WS_OFF_PT);
    float* xp = (float*)(ws + WS_OFF_XP);
    unsigned long long* part = (unsigned long long*)(ws + WS_OFF_PART);

    k_transpose_P<<<CB_VOCAB * CB_DIM / (256 * 16), 256, 0, stream>>>(P, Pt); // 8192 elems -> 32 blocks
    k_proj<<<N_ROWS * CB_DIM / 256, 256, 0, stream>>>(x, Pt, xp);             // 1024 blocks
    k_scan<<<ROW_BLOCKS * NCHUNKS, 256, 0, stream>>>(xp, CB, part);           // 512 blocks
    k_reduce<<<N_ROWS / 256, 256, 0, stream>>>(part, out);                    // 64 blocks
}

// Round 2
// 147.338 us; speedup vs baseline: 1.4041x; 1.4041x over previous
//
#include <hip/hip_runtime.h>
#include <stdint.h>

#define N_ROWS   16384
#define IN_DIM   512
#define CB_DIM   16
#define CB_VOCAB 8192

#define CODES_PER_CHUNK 128
#define NCHUNKS (CB_VOCAB / CODES_PER_CHUNK)        // 64
#define ROWS_PER_LANE 8
#define WAVES_PER_BLOCK 4
#define ROWS_PER_WAVE (64 * ROWS_PER_LANE)          // 512
#define ROWS_PER_BLOCK (ROWS_PER_WAVE * WAVES_PER_BLOCK) // 2048
#define ROW_BLOCKS (N_ROWS / ROWS_PER_BLOCK)        // 8

// workspace layout (bytes)
#define WS_OFF_XP   0                               // 16384*16*4 = 1 MB
#define WS_OFF_PART (1 << 20)                       // 64*16384*8 = 8 MB

// monotone float -> uint32 key (order-preserving for all finite floats)
__device__ __forceinline__ unsigned fkey(float f) {
    unsigned u = __float_as_uint(f);
    return (u & 0x80000000u) ? ~u : (u | 0x80000000u);
}

// ---------------- kernel 1: xp = x @ P -------------------------------------
// 256 blocks x 256 threads. Block handles 64 rows; wave w covers k-range
// [128w, 128w+128). Thread-per-row: 16 independent accumulators (ILP),
// x read exactly once, P broadcast from LDS (natural [k][16] layout).
// In-block LDS reduction of the 4 k-partials -> coalesced float4 store.
__global__ __launch_bounds__(256, 1)
void k_proj(const float* __restrict__ x, const float* __restrict__ P,
            float* __restrict__ xp) {
    __shared__ float4 Ps[IN_DIM * 4];          // P [512][16] f32 = 32 KB
    __shared__ float  accs[WAVES_PER_BLOCK][64][16];  // 16 KB

    // stage P (contiguous, coalesced)
    for (int i = threadIdx.x; i < IN_DIM * 4; i += 256)
        Ps[i] = ((const float4*)P)[i];
    __syncthreads();

    const int wave  = threadIdx.x >> 6;
    const int lane  = threadIdx.x & 63;
    const int row   = blockIdx.x * 64 + lane;
    const int kbase = wave * 128;

    float acc[16];
#pragma unroll
    for (int c = 0; c < 16; ++c) acc[c] = 0.0f;

    const float4* xr = (const float4*)(x + (size_t)row * IN_DIM + kbase);
    const float4* Pk = Ps + (size_t)kbase * 4;   // Ps[k*4 + q]

#pragma unroll 4
    for (int i = 0; i < 32; ++i) {               // 32 float4's of x
        float4 xv = xr[i];
        float xs[4] = {xv.x, xv.y, xv.z, xv.w};
#pragma unroll
        for (int kk = 0; kk < 4; ++kk) {
#pragma unroll
            for (int q = 0; q < 4; ++q) {
                float4 p = Pk[(i * 4 + kk) * 4 + q];
                acc[q * 4 + 0] += xs[kk] * p.x;
                acc[q * 4 + 1] += xs[kk] * p.y;
                acc[q * 4 + 2] += xs[kk] * p.z;
                acc[q * 4 + 3] += xs[kk] * p.w;
            }
        }
    }

    // deposit partials
#pragma unroll
    for (int c = 0; c < 16; ++c) accs[wave][lane][c] = acc[c];
    __syncthreads();

    // 256 threads: each sums one output float4 across the 4 wave-partials
    {
        int j  = threadIdx.x;       // float4 index in block's 64x16 output
        int r  = j >> 2;
        int c4 = j & 3;
        float4 s = {0.f, 0.f, 0.f, 0.f};
#pragma unroll
        for (int p = 0; p < WAVES_PER_BLOCK; ++p) {
            float4 v = *(const float4*)&accs[p][r][c4 * 4];
            s.x += v.x; s.y += v.y; s.z += v.z; s.w += v.w;
        }
        ((float4*)(xp + (size_t)blockIdx.x * 64 * CB_DIM))[j] = s;
    }
}

// ---------------- kernel 2: fused sim + per-chunk argmax --------------------
// grid: ROW_BLOCKS * NCHUNKS blocks of 256 threads (4 waves)
// each lane owns 8 rows (xp in regs); codes of the chunk broadcast from LDS.
__global__ __launch_bounds__(256, 2)
void k_scan(const float* __restrict__ xp, const float* __restrict__ CB,
            unsigned long long* __restrict__ part) {
    __shared__ float4 cbs[CODES_PER_CHUNK * 4];      // 128 codes * 16 f32 = 8 KB

    int chunk  = blockIdx.x & (NCHUNKS - 1);
    int rowblk = blockIdx.x >> 6;                    // / NCHUNKS

    // stage codebook chunk -> LDS (coalesced float4)
    {
        const float4* src = (const float4*)(CB + (size_t)chunk * CODES_PER_CHUNK * CB_DIM);
        for (int i = threadIdx.x; i < CODES_PER_CHUNK * 4; i += 256)
            cbs[i] = src[i];
    }
    __syncthreads();

    int wave = threadIdx.x >> 6;
    int lane = threadIdx.x & 63;
    int rowbase = rowblk * ROWS_PER_BLOCK + wave * ROWS_PER_WAVE + lane;

    // load 8 rows of xp into registers (coalesced: lanes stride 64 B)
    float4 A[ROWS_PER_LANE][4];
#pragma unroll
    for (int r = 0; r < ROWS_PER_LANE; ++r) {
        const float4* p = (const float4*)(xp + (size_t)(rowbase + 64 * r) * CB_DIM);
        A[r][0] = p[0]; A[r][1] = p[1]; A[r][2] = p[2]; A[r][3] = p[3];
    }

    float bestv[ROWS_PER_LANE];
    int   besti[ROWS_PER_LANE];
#pragma unroll
    for (int r = 0; r < ROWS_PER_LANE; ++r) { bestv[r] = -INFINITY; besti[r] = 0; }

    int jbase = chunk * CODES_PER_CHUNK;
    for (int j = 0; j < CODES_PER_CHUNK; ++j) {
        float4 c0 = cbs[j * 4 + 0];
        float4 c1 = cbs[j * 4 + 1];
        float4 c2 = cbs[j * 4 + 2];
        float4 c3 = cbs[j * 4 + 3];
#pragma unroll
        for (int r = 0; r < ROWS_PER_LANE; ++r) {
            float s = A[r][0].x * c0.x + A[r][0].y * c0.y + A[r][0].z * c0.z + A[r][0].w * c0.w
                    + A[r][1].x * c1.x + A[r][1].y * c1.y + A[r][1].z * c1.z + A[r][1].w * c1.w
                    + A[r][2].x * c2.x + A[r][2].y * c2.y + A[r][2].z * c2.z + A[r][2].w * c2.w
                    + A[r][3].x * c3.x + A[r][3].y * c3.y + A[r][3].z * c3.z + A[r][3].w * c3.w;
            if (s > bestv[r]) { bestv[r] = s; besti[r] = jbase + j; }  // strict > : first occurrence wins
        }
    }

    // pack (key << 32) | ~idx : max-reduce picks larger value, then smaller idx
#pragma unroll
    for (int r = 0; r < ROWS_PER_LANE; ++r) {
        unsigned long long packed =
            ((unsigned long long)fkey(bestv[r]) << 32) |
            (unsigned long long)(0xFFFFFFFFu - (unsigned)besti[r]);
        part[(size_t)chunk * N_ROWS + rowbase + 64 * r] = packed;
    }
}

// ---------------- kernel 3: reduce partials -> int32 indices ----------------
__global__ void k_reduce(const unsigned long long* __restrict__ part,
                         int* __restrict__ out) {
    int row = blockIdx.x * 256 + threadIdx.x;        // [0, 16384)
    unsigned long long best = 0ull;
#pragma unroll 8
    for (int c = 0; c < NCHUNKS; ++c) {
        unsigned long long v = part[(size_t)c * N_ROWS + row];
        best = (v > best) ? v : best;
    }
    out[row] = (int)(0xFFFFFFFFu - (unsigned)(best & 0xFFFFFFFFull));
}

extern "C" void kernel_launch(void* const* d_in, const int* in_sizes, int n_in,
                              void* d_out, int out_size, void* d_ws, size_t ws_size,
                              hipStream_t stream) {
    const float* x  = (const float*)d_in[0];   // [16384, 512]
    const float* P  = (const float*)d_in[1];   // [512, 16]
    const float* CB = (const float*)d_in[2];   // [8192, 16]
    int* out = (int*)d_out;                    // [16384] int32

    char* ws = (char*)d_ws;
    float* xp = (float*)(ws + WS_OFF_XP);
    unsigned long long* part = (unsigned long long*)(ws + WS_OFF_PART);

    k_proj<<<N_ROWS / 64, 256, 0, stream>>>(x, P, xp);              // 256 blocks
    k_scan<<<ROW_BLOCKS * NCHUNKS, 256, 0, stream>>>(xp, CB, part); // 512 blocks
    k_reduce<<<N_ROWS / 256, 256, 0, stream>>>(part, out);          // 64 blocks
}

// Round 3
// 146.176 us; speedup vs baseline: 1.4152x; 1.0080x over previous
//
#include <hip/hip_runtime.h>
#include <stdint.h>

#define N_ROWS   16384
#define IN_DIM   512
#define CB_DIM   16
#define CB_VOCAB 8192

#define CODES_PER_CHUNK 128
#define NCHUNKS (CB_VOCAB / CODES_PER_CHUNK)        // 64
#define ROWS_PER_LANE 4                             // A-tile = 64 VGPRs, stays resident
#define WAVES_PER_BLOCK 4
#define ROWS_PER_WAVE (64 * ROWS_PER_LANE)          // 256
#define ROWS_PER_BLOCK (ROWS_PER_WAVE * WAVES_PER_BLOCK) // 1024
#define ROW_BLOCKS (N_ROWS / ROWS_PER_BLOCK)        // 16

// workspace layout (bytes)
#define WS_OFF_XP   0                               // 16384*16*4 = 1 MB
#define WS_OFF_PART (1 << 20)                       // 64*16384*8 = 8 MB

// monotone float -> uint32 key (order-preserving for all finite floats)
__device__ __forceinline__ unsigned fkey(float f) {
    unsigned u = __float_as_uint(f);
    return (u & 0x80000000u) ? ~u : (u | 0x80000000u);
}

// ---------------- kernel 1: xp = x @ P -------------------------------------
// 256 blocks x 256 threads. Block handles 64 rows; wave w covers k-range
// [128w, 128w+128). Thread-per-row: 16 independent accumulators (ILP),
// x read exactly once, P broadcast from LDS (natural [k][16] layout).
__global__ __launch_bounds__(256, 1)
void k_proj(const float* __restrict__ x, const float* __restrict__ P,
            float* __restrict__ xp) {
    __shared__ float4 Ps[IN_DIM * 4];          // P [512][16] f32 = 32 KB
    __shared__ float  accs[WAVES_PER_BLOCK][64][16];  // 16 KB

    for (int i = threadIdx.x; i < IN_DIM * 4; i += 256)
        Ps[i] = ((const float4*)P)[i];
    __syncthreads();

    const int wave  = threadIdx.x >> 6;
    const int lane  = threadIdx.x & 63;
    const int row   = blockIdx.x * 64 + lane;
    const int kbase = wave * 128;

    float acc[16];
#pragma unroll
    for (int c = 0; c < 16; ++c) acc[c] = 0.0f;

    const float4* xr = (const float4*)(x + (size_t)row * IN_DIM + kbase);
    const float4* Pk = Ps + (size_t)kbase * 4;   // Ps[k*4 + q]

#pragma unroll 4
    for (int i = 0; i < 32; ++i) {               // 32 float4's of x
        float4 xv = xr[i];
        float xs[4] = {xv.x, xv.y, xv.z, xv.w};
#pragma unroll
        for (int kk = 0; kk < 4; ++kk) {
#pragma unroll
            for (int q = 0; q < 4; ++q) {
                float4 p = Pk[(i * 4 + kk) * 4 + q];
                acc[q * 4 + 0] += xs[kk] * p.x;
                acc[q * 4 + 1] += xs[kk] * p.y;
                acc[q * 4 + 2] += xs[kk] * p.z;
                acc[q * 4 + 3] += xs[kk] * p.w;
            }
        }
    }

#pragma unroll
    for (int c = 0; c < 16; ++c) accs[wave][lane][c] = acc[c];
    __syncthreads();

    {
        int j  = threadIdx.x;       // float4 index in block's 64x16 output
        int r  = j >> 2;
        int c4 = j & 3;
        float4 s = {0.f, 0.f, 0.f, 0.f};
#pragma unroll
        for (int p = 0; p < WAVES_PER_BLOCK; ++p) {
            float4 v = *(const float4*)&accs[p][r][c4 * 4];
            s.x += v.x; s.y += v.y; s.z += v.z; s.w += v.w;
        }
        ((float4*)(xp + (size_t)blockIdx.x * 64 * CB_DIM))[j] = s;
    }
}

// ---------------- kernel 2: fused sim + per-chunk argmax --------------------
// grid: ROW_BLOCKS * NCHUNKS = 1024 blocks of 256 threads (4 blocks/CU).
// each lane owns 4 rows (64 VGPRs, register-resident); codes broadcast from LDS.
__global__ __launch_bounds__(256, 4)
void k_scan(const float* __restrict__ xp, const float* __restrict__ CB,
            unsigned long long* __restrict__ part) {
    __shared__ float4 cbs[CODES_PER_CHUNK * 4];      // 128 codes * 16 f32 = 8 KB

    int chunk  = blockIdx.x & (NCHUNKS - 1);
    int rowblk = blockIdx.x >> 6;                    // / NCHUNKS

    {
        const float4* src = (const float4*)(CB + (size_t)chunk * CODES_PER_CHUNK * CB_DIM);
        for (int i = threadIdx.x; i < CODES_PER_CHUNK * 4; i += 256)
            cbs[i] = src[i];
    }
    __syncthreads();

    int wave = threadIdx.x >> 6;
    int lane = threadIdx.x & 63;
    int rowbase = rowblk * ROWS_PER_BLOCK + wave * ROWS_PER_WAVE + lane;

    // load 4 rows of xp into registers (coalesced: lanes stride 64 B)
    float4 A[ROWS_PER_LANE][4];
#pragma unroll
    for (int r = 0; r < ROWS_PER_LANE; ++r) {
        const float4* p = (const float4*)(xp + (size_t)(rowbase + 64 * r) * CB_DIM);
        A[r][0] = p[0]; A[r][1] = p[1]; A[r][2] = p[2]; A[r][3] = p[3];
    }

    float bestv[ROWS_PER_LANE];
    int   besti[ROWS_PER_LANE];
#pragma unroll
    for (int r = 0; r < ROWS_PER_LANE; ++r) { bestv[r] = -INFINITY; besti[r] = 0; }

    int jbase = chunk * CODES_PER_CHUNK;
    for (int j = 0; j < CODES_PER_CHUNK; ++j) {
        float4 c0 = cbs[j * 4 + 0];
        float4 c1 = cbs[j * 4 + 1];
        float4 c2 = cbs[j * 4 + 2];
        float4 c3 = cbs[j * 4 + 3];
#pragma unroll
        for (int r = 0; r < ROWS_PER_LANE; ++r) {
            float s = A[r][0].x * c0.x + A[r][0].y * c0.y + A[r][0].z * c0.z + A[r][0].w * c0.w
                    + A[r][1].x * c1.x + A[r][1].y * c1.y + A[r][1].z * c1.z + A[r][1].w * c1.w
                    + A[r][2].x * c2.x + A[r][2].y * c2.y + A[r][2].z * c2.z + A[r][2].w * c2.w
                    + A[r][3].x * c3.x + A[r][3].y * c3.y + A[r][3].z * c3.z + A[r][3].w * c3.w;
            if (s > bestv[r]) { bestv[r] = s; besti[r] = jbase + j; }  // strict > : first occurrence wins
        }
    }

#pragma unroll
    for (int r = 0; r < ROWS_PER_LANE; ++r) {
        unsigned long long packed =
            ((unsigned long long)fkey(bestv[r]) << 32) |
            (unsigned long long)(0xFFFFFFFFu - (unsigned)besti[r]);
        part[(size_t)chunk * N_ROWS + rowbase + 64 * r] = packed;
    }
}

// ---------------- kernel 3: reduce partials -> int32 indices ----------------
// 256 blocks x 256 threads; block owns 64 rows; thread (row, chunk-group of 16).
__global__ __launch_bounds__(256, 4)
void k_reduce(const unsigned long long* __restrict__ part,
              int* __restrict__ out) {
    __shared__ unsigned long long red[4][64];
    int rlane = threadIdx.x & 63;
    int grp   = threadIdx.x >> 6;                    // 0..3
    int row   = blockIdx.x * 64 + rlane;

    unsigned long long best = 0ull;
#pragma unroll
    for (int c = grp * 16; c < grp * 16 + 16; ++c) {
        unsigned long long v = part[(size_t)c * N_ROWS + row];
        best = (v > best) ? v : best;
    }
    red[grp][rlane] = best;
    __syncthreads();

    if (threadIdx.x < 64) {
        unsigned long long b = red[0][threadIdx.x];
        unsigned long long v1 = red[1][threadIdx.x];
        unsigned long long v2 = red[2][threadIdx.x];
        unsigned long long v3 = red[3][threadIdx.x];
        b = (v1 > b) ? v1 : b;
        b = (v2 > b) ? v2 : b;
        b = (v3 > b) ? v3 : b;
        out[blockIdx.x * 64 + threadIdx.x] =
            (int)(0xFFFFFFFFu - (unsigned)(b & 0xFFFFFFFFull));
    }
}

extern "C" void kernel_launch(void* const* d_in, const int* in_sizes, int n_in,
                              void* d_out, int out_size, void* d_ws, size_t ws_size,
                              hipStream_t stream) {
    const float* x  = (const float*)d_in[0];   // [16384, 512]
    const float* P  = (const float*)d_in[1];   // [512, 16]
    const float* CB = (const float*)d_in[2];   // [8192, 16]
    int* out = (int*)d_out;                    // [16384] int32

    char* ws = (char*)d_ws;
    float* xp = (float*)(ws + WS_OFF_XP);
    unsigned long long* part = (unsigned long long*)(ws + WS_OFF_PART);

    k_proj<<<N_ROWS / 64, 256, 0, stream>>>(x, P, xp);              // 256 blocks
    k_scan<<<ROW_BLOCKS * NCHUNKS, 256, 0, stream>>>(xp, CB, part); // 1024 blocks
    k_reduce<<<N_ROWS / 64, 256, 0, stream>>>(part, out);           // 256 blocks
}